// Round 1
// baseline (1492.024 us; speedup 1.0000x reference)
//
#include <hip/hip_runtime.h>
#include <hip/hip_bf16.h>

// ---------------------------------------------------------------------------
// InvSlotAttentionGuide: CNN encoder -> pos embed -> MLP -> slot attention
// with MESH-Sinkhorn (manual reverse-mode through 5 sinkhorn iters).
// R18: sa_kernel 512 -> 1024 threads, ONE token per thread (per-thread
// Sinkhorn state 26 -> 14 floats), grid stays 16 (one batch per block).
// Column LSE reductions split across 16 waves (2 waves/slot, 8 elems/lane)
// with an LDS combine. R16's failure was packing 2 BATCHES/block (grid 8,
// state still 26 floats -> spill); this keeps grid=16 and halves state.
// __launch_bounds__(1024,4): 16 waves/CU -> 128 VGPR cap.
// ---------------------------------------------------------------------------

#define LN_EPS 1e-5f
#define SEPS 1e-8f
#define LN8 2.0794415416798357f

__device__ inline float ldf(float x) { return x; }
__device__ inline float ldf(__hip_bfloat16 x) { return __bfloat162float(x); }
__device__ inline void stf(float* p, float v) { *p = v; }
__device__ inline void stf(__hip_bfloat16* p, float v) { *p = __float2bfloat16(v); }

__device__ inline float wmaxall(float v) {
#pragma unroll
  for (int o = 32; o; o >>= 1) v = fmaxf(v, __shfl_down(v, o));
  return __shfl(v, 0);
}
__device__ inline float wsumall(float v) {
#pragma unroll
  for (int o = 32; o; o >>= 1) v += __shfl_down(v, o);
  return __shfl(v, 0);
}
__device__ inline int wsumi(int v) {
#pragma unroll
  for (int o = 32; o; o >>= 1) v += __shfl_down(v, o);
  return __shfl(v, 0);
}
__device__ inline float fast_sigmoid(float x) { return 1.f / (1.f + __expf(-x)); }
__device__ inline float fast_tanh(float x) { return 1.f - 2.f / (__expf(2.f * x) + 1.f); }

// ---------------------------------------------------------------------------
__global__ __launch_bounds__(64) void sniff_kernel(const unsigned int* __restrict__ img,
                                                   int* __restrict__ flag) {
  int cnt = 0;
  for (int i = threadIdx.x; i < 512; i += 64) {
    unsigned lo = img[i] & 0xFFFFu;
    int e = (int)((lo >> 7) & 0xFFu);
    cnt += (e >= 96 && e <= 140) ? 1 : 0;
  }
  cnt = wsumi(cnt);
  if (threadIdx.x == 0) *flag = (cnt >= 300) ? 1 : 0;
}

struct CvtArgs {
  const void* src[39];
  long off[40];
};

__global__ __launch_bounds__(256) void convert_kernel(CvtArgs a, const int* __restrict__ flag,
                                                      float* __restrict__ dst, long total) {
  const int isbf = *flag;
  for (long g = (long)blockIdx.x * 256 + threadIdx.x; g < total; g += (long)gridDim.x * 256) {
    int lo = 0, hi = 38;
    while (lo < hi) {
      int mid = (lo + hi + 1) >> 1;
      if (a.off[mid] <= g) lo = mid; else hi = mid - 1;
    }
    long li = g - a.off[lo];
    float v;
    if (isbf) v = __bfloat162float(((const __hip_bfloat16*)a.src[lo])[li]);
    else      v = ((const float*)a.src[lo])[li];
    dst[g] = v;
  }
}

// ---------------------------------------------------------------------------
struct TwArgs {
  long soff[9]; long doff[9]; int R[9]; int C[9];
};

__global__ __launch_bounds__(256) void transw_kernel(const float* __restrict__ cvt,
                                                     float* __restrict__ tws, TwArgs a) {
  int m = blockIdx.x;
  const float* S = cvt + a.soff[m];
  float* D = tws + a.doff[m];
  int R = a.R[m], C = a.C[m];
  for (int idx = threadIdx.x; idx < R * C; idx += 256) {
    int i = idx / C, j = idx - i * C;
    D[j * R + i] = S[idx];
  }
}

// ---------------------------------------------------------------------------
// Direct 5x5 conv + bias + relu (R13-exact): 16x16 tile x 16 oc per block,
// float4 win loads from padded rows, wt[tap][16] broadcast b128.
// ---------------------------------------------------------------------------
template <int S, typename TIN, typename TOUT>
__global__ __launch_bounds__(256) void conv5x5(
    const TIN* __restrict__ in, const float* __restrict__ wgt,
    const float* __restrict__ bias, TOUT* __restrict__ out,
    int Cin, int H, int W, int Ho, int Wo, int Cout, int tilesX) {
  constexpr int P = 15 * S + 5;
  constexpr int PP = (S == 1) ? 20 : 36;
  constexpr int NCH = (S == 1) ? 2 : 3;
  __shared__ __align__(16) float patch[P * PP];
  __shared__ float wt16[25 * 16];
  const int b = blockIdx.z;
  const int ocg = blockIdx.y * 16;
  const int ty0 = (blockIdx.x / tilesX) * 16, tx0 = (blockIdx.x % tilesX) * 16;
  const int og = threadIdx.x >> 6;
  const int r = (threadIdx.x >> 2) & 15;
  const int rx = threadIdx.x & 3;
  const int iy0 = ty0 * S - 2, ix0 = tx0 * S - 2;
  float acc[4][4];
#pragma unroll
  for (int p = 0; p < 4; p++)
#pragma unroll
    for (int j = 0; j < 4; j++) acc[p][j] = 0.f;

  for (int ci = 0; ci < Cin; ++ci) {
    const TIN* inp = in + ((long)b * Cin + ci) * (long)H * W;
    for (int idx = threadIdx.x; idx < P * P; idx += 256) {
      int py = idx / P, px = idx - py * P;
      int iy = iy0 + py, ix = ix0 + px;
      float v = 0.f;
      if (iy >= 0 && iy < H && ix >= 0 && ix < W) v = ldf(inp[(long)iy * W + ix]);
      patch[py * PP + px] = v;
    }
    for (int idx = threadIdx.x; idx < 16 * 25; idx += 256) {
      int tap = idx >> 4, j = idx & 15;
      wt16[idx] = wgt[((long)(ocg + j) * Cin + ci) * 25 + tap];
    }
    __syncthreads();
#pragma unroll
    for (int ky = 0; ky < 5; ky++) {
      float win[4 * NCH];
      const float* bp = &patch[(r * S + ky) * PP + rx * 4 * S];
#pragma unroll
      for (int c = 0; c < NCH; c++) {
        float4 t4 = *(const float4*)(bp + 4 * c);
        win[4 * c + 0] = t4.x;
        win[4 * c + 1] = t4.y;
        win[4 * c + 2] = t4.z;
        win[4 * c + 3] = t4.w;
      }
#pragma unroll
      for (int kx = 0; kx < 5; kx++) {
        const float4 wv = *(const float4*)&wt16[(ky * 5 + kx) * 16 + og * 4];
#pragma unroll
        for (int p = 0; p < 4; p++) {
          float iv = win[p * S + kx];
          acc[p][0] += iv * wv.x;
          acc[p][1] += iv * wv.y;
          acc[p][2] += iv * wv.z;
          acc[p][3] += iv * wv.w;
        }
      }
    }
    __syncthreads();
  }
  const int oy = ty0 + r, ox0 = tx0 + rx * 4;
#pragma unroll
  for (int j = 0; j < 4; j++) {
    int oc = ocg + og * 4 + j;
    float bs = bias[oc];
    TOUT* op = &out[(((long)b * Cout + oc) * Ho + oy) * Wo + ox0];
#pragma unroll
    for (int p = 0; p < 4; p++) stf(&op[p], fmaxf(acc[p][j] + bs, 0.f));
  }
}

// ---------------------------------------------------------------------------
// Per-token (one wave): inline pos-embed from act4 -> MLP -> LN -> k
// (l2norm, stored TRANSPOSED [d][n]), v, mwi logit.  (R13-exact)
// ---------------------------------------------------------------------------
__global__ __launch_bounds__(64) void token_kernel(
    const float* __restrict__ act4, const float* __restrict__ pos_w,
    const float* __restrict__ pos_b,
    const float* __restrict__ mlp1T, const float* __restrict__ mlp1_b,
    const float* __restrict__ mlp2T, const float* __restrict__ mlp2_b,
    const float* __restrict__ lnin_w, const float* __restrict__ lnin_b,
    const float* __restrict__ wkT, const float* __restrict__ wvT,
    const float* __restrict__ mwi_w, const float* __restrict__ mwi_b,
    float* __restrict__ knT_out, float* __restrict__ v_out, float* __restrict__ lg_out) {
  const int t = blockIdx.x, i = threadIdx.x;
  const int b = t >> 10, nn = t & 1023;
  const int h = nn >> 5, w = nn & 31;
  __shared__ float f[64], h1[64], inp[64];
  {
    float gh = h * (1.f / 31.f), gw = w * (1.f / 31.f);
    float e = gh * pos_w[i * 4 + 0] + gw * pos_w[i * 4 + 1] +
              (1.f - gh) * pos_w[i * 4 + 2] + (1.f - gw) * pos_w[i * 4 + 3] + pos_b[i];
    f[i] = act4[(((long)b * 64 + i) * 32 + h) * 32 + w] + e;
  }
  __syncthreads();
  float acc = 0.f;
  for (int j = 0; j < 64; j++) acc += f[j] * mlp1T[j * 64 + i];
  h1[i] = fmaxf(acc + mlp1_b[i], 0.f);
  __syncthreads();
  acc = 0.f;
  for (int j = 0; j < 64; j++) acc += h1[j] * mlp2T[j * 64 + i];
  float x = acc + mlp2_b[i];
  float m = wsumall(x) * (1.f / 64.f);
  float d0 = x - m;
  float var = wsumall(d0 * d0) * (1.f / 64.f);
  float xin = d0 * rsqrtf(var + LN_EPS) * lnin_w[i] + lnin_b[i];
  inp[i] = xin;
  __syncthreads();
  float kv = 0.f, vv = 0.f;
  for (int j = 0; j < 64; j++) {
    float ij = inp[j];
    kv += ij * wkT[j * 64 + i];
    vv += ij * wvT[j * 64 + i];
  }
  float ss = wsumall(kv * kv);
  knT_out[(long)b * 65536 + i * 1024 + nn] = kv / fmaxf(sqrtf(ss), 1e-12f);
  v_out[(long)t * 64 + i] = vv;
  float lg = wsumall(xin * mwi_w[i]);
  if (i == 0) lg_out[t] = lg + mwi_b[0];
}

// ---------------------------------------------------------------------------
// Slot-attention loop (R18): 1024 threads = 16 waves, ONE token per thread.
// LSE-reuse fused backward + max-free column LSEs. Column reductions split
// 2 waves/slot (8 elems/lane) + LDS combine. Slot-side phases use tid<512.
// ---------------------------------------------------------------------------
__global__ __launch_bounds__(1024, 4) void sa_kernel(
    const float* __restrict__ knT_g, const float* __restrict__ v_g,
    const float* __restrict__ la_g, const float* __restrict__ noise,
    const float* __restrict__ mu_w, const float* __restrict__ sg_w,
    const float* __restrict__ lnsl_w, const float* __restrict__ lnsl_b,
    const float* __restrict__ mws_w, const float* __restrict__ mws_b,
    const float* __restrict__ wqT,
    const float* __restrict__ wihT, const float* __restrict__ whhT,
    const float* __restrict__ bih, const float* __restrict__ bhh,
    const float* __restrict__ lnff_w, const float* __restrict__ lnff_b,
    const float* __restrict__ fc1T, const float* __restrict__ fc1_b,
    const float* __restrict__ fc2T, const float* __restrict__ fc2_b,
    float* __restrict__ out) {
  const int b = blockIdx.x, tid = threadIdx.x;
  const int wv = tid >> 6, ln = tid & 63;

  __shared__ float sCt[8192];
  __shared__ float sLa[1024], sU[1024], sGu[1024], sRow[1024], sHid[1024];
  __shared__ float sVh[48], sV[8], sGv[8], sLb[8], sBm[8];
  __shared__ float sWred[32];
  __shared__ float sLaMax;
  __shared__ float sSlots[512], sNorm[512], sQn[512], sUpd[512];

  const float* knt = knT_g + (long)b * 65536;
  const float* vf = v_g + (long)b * 65536;
  float u_hist[5];
  float gPr[8];
  float gInit;

  if (tid < 512) {
    int dd = tid & 63;
    sSlots[tid] = mu_w[dd] + (fabsf(sg_w[dd]) + SEPS) * noise[(long)b * 512 + tid];
  }
  sLa[tid] = la_g[b * 1024 + tid];
  __syncthreads();
  {  // fused la: sLa <- raw - LSE + ln8 ; record laMax  (16-wave version)
    float a0 = sLa[tid];
    float m0 = wmaxall(a0);
    if (ln == 0) sWred[wv] = m0;
    __syncthreads();
    float M = sWred[0];
#pragma unroll
    for (int s = 1; s < 16; s++) M = fmaxf(M, sWred[s]);
    float e0 = wsumall(__expf(a0 - M));
    if (ln == 0) sWred[16 + wv] = e0;
    __syncthreads();
    float SS = 0.f;
#pragma unroll
    for (int s = 0; s < 16; s++) SS += sWred[16 + s];
    float lse = M + __logf(SS);
    sLa[tid] = a0 - lse + LN8;
    if (tid == 0) sLaMax = M - lse + LN8;
  }
  __syncthreads();
  const float laMax = sLaMax;

  for (int it = 0; it < 3; ++it) {
    if (tid < 512) {
      float x = sSlots[tid];
      float m = wsumall(x) * (1.f / 64.f);
      float d0 = x - m;
      float var = wsumall(d0 * d0) * (1.f / 64.f);
      float xn = d0 * rsqrtf(var + LN_EPS) * lnsl_w[ln] + lnsl_b[ln];
      sNorm[tid] = xn;
      float bmv = wsumall(xn * mws_w[ln]);
      if (ln == 0) sBm[wv] = bmv + mws_b[0];
    }
    __syncthreads();
    if (tid == 0) {
      float mx = -1e30f;
      for (int s = 0; s < 8; s++) mx = fmaxf(mx, sBm[s]);
      float ss = 0.f;
      for (int s = 0; s < 8; s++) ss += __expf(sBm[s] - mx);
      float lse = mx + __logf(ss);
      for (int s = 0; s < 8; s++) sLb[s] = sBm[s] - lse + LN8;
    }
    if (tid < 512) {
      float acc = 0.f;
      for (int j = 0; j < 64; j++) acc += sNorm[wv * 64 + j] * wqT[j * 64 + ln];
      sQn[tid] = acc;
    }
    __syncthreads();
    if (tid < 512) {
      float qv = sQn[tid];
      float ss = wsumall(qv * qv);
      sQn[tid] = qv / fmaxf(sqrtf(ss), 1e-12f);
    }
    if (tid < 8) sV[tid] = 0.f;
    __syncthreads();

    {  // C = 1 - kn . qn   (one token per thread)
      const int n = tid;
      float acc[8];
#pragma unroll
      for (int s = 0; s < 8; s++) acc[s] = 0.f;
      for (int j = 0; j < 64; j++) {
        float kvv = knt[j * 1024 + n];
#pragma unroll
        for (int s = 0; s < 8; s++) acc[s] += kvv * sQn[s * 64 + j];
      }
#pragma unroll
      for (int s = 0; s < 8; s++) sCt[s * 1024 + n] = 1.f - acc[s];
    }
    __syncthreads();

    for (int m = 0; m < 4; m++) {
#pragma unroll
      for (int t = 1; t <= 5; t++) {
        if (t == 1 && tid < 8) sVh[tid] = sV[tid];
        {  // row (u) update: one token per thread
          const int n = tid;
          float mx = -1e30f;
#pragma unroll
          for (int s = 0; s < 8; s++) mx = fmaxf(mx, sV[s] - sCt[s * 1024 + n]);
          float ssum = 0.f;
#pragma unroll
          for (int s = 0; s < 8; s++) ssum += __expf(sV[s] - sCt[s * 1024 + n] - mx);
          float un = sLa[n] - (mx + __logf(ssum));
          sU[n] = un;
          u_hist[t - 1] = un;
        }
        __syncthreads();
        {  // column partial: 2 waves/slot, 8 elems/lane
          int s = wv & 7, hf = wv >> 3;
          float ms = laMax - sV[s];
          float ssum = 0.f;
          const int base = hf << 9;
          for (int n = base + ln; n < base + 512; n += 64)
            ssum += __expf(sU[n] - sCt[s * 1024 + n] - ms);
          ssum = wsumall(ssum);
          if (ln == 0) sWred[wv] = ssum;
        }
        __syncthreads();
        if (tid < 8) {
          float ms = laMax - sV[tid];
          float vs = sLb[tid] - (ms + __logf(sWred[tid] + sWred[tid + 8]));
          sV[tid] = vs;
          sVh[t * 8 + tid] = vs;
        }
        __syncthreads();
      }
      {  // entropy gradient seed
        {
          const int n = tid;
          float un = u_hist[4];
          float gul = 0.f;
#pragma unroll
          for (int s = 0; s < 8; s++) {
            float pi = __expf(un + sV[s] - sCt[s * 1024 + n]);
            float gl = -(__logf(pi + SEPS) + pi / (pi + SEPS)) * pi * (1.f / 16.f);
            gPr[s] = gl;
            gul += gl;
          }
          gInit = gul;
        }
        {
          int s = wv & 7, hf = wv >> 3;
          float vs = sV[s];
          float acc = 0.f;
          const int base = hf << 9;
          for (int n = base + ln; n < base + 512; n += 64) {
            float pi = __expf(sU[n] + vs - sCt[s * 1024 + n]);
            acc += -(__logf(pi + SEPS) + pi / (pi + SEPS)) * pi * (1.f / 16.f);
          }
          acc = wsumall(acc);
          if (ln == 0) sWred[wv] = acc;
        }
      }
      __syncthreads();
      if (tid < 8) sGv[tid] = sWred[tid] + sWred[tid + 8];
      __syncthreads();
#pragma unroll
      for (int t = 5; t >= 1; t--) {
        {  // backward row step
          const int n = tid;
          float un = u_hist[t - 1];
          float gul = (t == 5) ? gInit : 0.f;
#pragma unroll
          for (int s = 0; s < 8; s++) {
            float t2 = sGv[s] * __expf(un - sCt[s * 1024 + n] - (sLb[s] - sVh[t * 8 + s]));
            gPr[s] -= t2;
            gul -= t2;
          }
          float rowlse = sLa[n] - un;
#pragma unroll
          for (int s = 0; s < 8; s++)
            gPr[s] -= gul * __expf(sVh[(t - 1) * 8 + s] - sCt[s * 1024 + n] - rowlse);
          sGu[n] = gul;
          sRow[n] = rowlse;
          if (t == 1) {
#pragma unroll
            for (int s = 0; s < 8; s++) sCt[s * 1024 + n] += gPr[s];
          }
        }
        if (t == 1 && tid < 8) sV[tid] = sVh[40 + tid];
        __syncthreads();
        if (t > 1) {
          {  // backward column partial
            int s = wv & 7, hf = wv >> 3;
            float vvh = sVh[(t - 1) * 8 + s];
            float acc = 0.f;
            const int base = hf << 9;
            for (int n = base + ln; n < base + 512; n += 64)
              acc += sGu[n] * __expf(vvh - sCt[s * 1024 + n] - sRow[n]);
            acc = wsumall(acc);
            if (ln == 0) sWred[wv] = acc;
          }
          __syncthreads();
          if (tid < 8) sGv[tid] = -(sWred[tid] + sWred[tid + 8]);
          __syncthreads();
        }
      }
    }

    for (int t = 0; t < 5; t++) {  // final warm-start sinkhorn
      {
        const int n = tid;
        float mx = -1e30f;
#pragma unroll
        for (int s = 0; s < 8; s++) mx = fmaxf(mx, sV[s] - sCt[s * 1024 + n]);
        float ssum = 0.f;
#pragma unroll
        for (int s = 0; s < 8; s++) ssum += __expf(sV[s] - sCt[s * 1024 + n] - mx);
        sU[n] = sLa[n] - (mx + __logf(ssum));
      }
      __syncthreads();
      {
        int s = wv & 7, hf = wv >> 3;
        float ms = laMax - sV[s];
        float ssum = 0.f;
        const int base = hf << 9;
        for (int n = base + ln; n < base + 512; n += 64)
          ssum += __expf(sU[n] - sCt[s * 1024 + n] - ms);
        ssum = wsumall(ssum);
        if (ln == 0) sWred[wv] = ssum;
      }
      __syncthreads();
      if (tid < 8)
        sV[tid] = sLb[tid] - ((laMax - sV[tid]) + __logf(sWred[tid] + sWred[tid + 8]));
      __syncthreads();
    }
    {  // pi
      const int n = tid;
      float un = sU[n];
#pragma unroll
      for (int s = 0; s < 8; s++) sCt[s * 1024 + n] = __expf(un + sV[s] - sCt[s * 1024 + n]);
    }
    __syncthreads();
    if (it == 2) {
      for (int o = tid; o < 8192; o += 1024) out[8192 + (long)b * 8192 + o] = sCt[o];
    }
    {  // updates = attn . v  (split over 2 half-ranges of n, partials in sHid)
      int p = tid >> 9;
      int r = tid & 511;
      int s = r >> 6, dd = r & 63;
      const int base = p << 9;
      float acc = 0.f;
      for (int n = 0; n < 512; n++) acc += sCt[s * 1024 + base + n] * vf[(base + n) * 64 + dd];
      sHid[tid] = acc;
    }
    __syncthreads();
    if (tid < 512) sUpd[tid] = sHid[tid] + sHid[tid + 512];
    __syncthreads();
    float newslot = 0.f;
    if (tid < 512) {  // GRU
      int i = ln;
      const float* x = &sUpd[wv * 64];
      const float* h = &sSlots[wv * 64];
      float gir = 0, giz = 0, gin = 0, ghr = 0, ghz = 0, ghn = 0;
      for (int j = 0; j < 64; j++) {
        float xv = x[j], hv = h[j];
        gir += xv * wihT[j * 192 + i];
        giz += xv * wihT[j * 192 + 64 + i];
        gin += xv * wihT[j * 192 + 128 + i];
        ghr += hv * whhT[j * 192 + i];
        ghz += hv * whhT[j * 192 + 64 + i];
        ghn += hv * whhT[j * 192 + 128 + i];
      }
      gir += bih[i]; giz += bih[64 + i]; gin += bih[128 + i];
      ghr += bhh[i]; ghz += bhh[64 + i]; ghn += bhh[128 + i];
      float rr = fast_sigmoid(gir + ghr);
      float z = fast_sigmoid(giz + ghz);
      float nn = fast_tanh(gin + rr * ghn);
      newslot = (1.f - z) * nn + z * h[i];
    }
    __syncthreads();
    if (tid < 512) sSlots[tid] = newslot;
    __syncthreads();
    if (tid < 512) {
      float x = sSlots[tid];
      float m = wsumall(x) * (1.f / 64.f);
      float d0 = x - m;
      float var = wsumall(d0 * d0) * (1.f / 64.f);
      sNorm[tid] = d0 * rsqrtf(var + LN_EPS) * lnff_w[ln] + lnff_b[ln];
    }
    __syncthreads();
    {  // fc1: one output per thread
      int s = tid >> 7, k2 = tid & 127;
      float acc = 0.f;
      for (int j = 0; j < 64; j++) acc += sNorm[s * 64 + j] * fc1T[j * 128 + k2];
      sHid[tid] = fmaxf(acc + fc1_b[k2], 0.f);
    }
    __syncthreads();
    if (tid < 512) {
      float acc = 0.f;
      for (int j = 0; j < 128; j++) acc += sHid[wv * 128 + j] * fc2T[j * 64 + ln];
      newslot = sSlots[tid] + acc + fc2_b[ln];
    }
    __syncthreads();
    if (tid < 512) sSlots[tid] = newslot;
    __syncthreads();
  }
  if (tid < 512) out[(long)b * 512 + tid] = sSlots[tid];
}

// ---------------------------------------------------------------------------
extern "C" void kernel_launch(void* const* d_in, const int* in_sizes, int n_in,
                              void* d_out, int out_size, void* d_ws, size_t ws_size,
                              hipStream_t stream) {
  (void)n_in; (void)out_size; (void)ws_size;
  char* ws = (char*)d_ws;
  float* cvt  = (float*)ws;                            // f32 inputs (4.7 MB)
  float* lgts = (float*)(ws + 5570560ull);             // RAW logits
  __hip_bfloat16* act1 = (__hip_bfloat16*)(ws + 5636096ull);   // bf16 33.55MB
  __hip_bfloat16* act2 = (__hip_bfloat16*)(ws + 39190528ull);  // bf16  8.39MB
  float* act3 = (float*)(ws + 5636096ull);             // over dead act1
  float* act4 = (float*)(ws + 9830400ull);             // live through token
  float* knT  = (float*)(ws + 14024704ull);            // 4 MB
  float* vf   = (float*)(ws + 18219008ull);            // 4 MB
  int*   flag = (int*)(ws + 47579136ull);
  float* tws  = (float*)(ws + 47583232ull);            // transposed weights

  CvtArgs ca;
  long total = 0;
  for (int i = 0; i < 39; i++) { ca.src[i] = d_in[i]; ca.off[i] = total; total += in_sizes[i]; }
  ca.off[39] = total;

  sniff_kernel<<<1, 64, 0, stream>>>((const unsigned int*)d_in[0], flag);
  convert_kernel<<<1024, 256, 0, stream>>>(ca, flag, cvt, total);

#define ARR(i) (cvt + ca.off[i])
  TwArgs ta;
  {
    const int src[9] = {12, 14, 18, 19, 20, 27, 28, 33, 35};
    const int R[9] = {64, 64, 64, 64, 64, 192, 192, 128, 64};
    const int C[9] = {64, 64, 64, 64, 64, 64, 64, 64, 128};
    long d = 0;
    for (int m2 = 0; m2 < 9; m2++) {
      ta.soff[m2] = ca.off[src[m2]];
      ta.doff[m2] = d;
      ta.R[m2] = R[m2];
      ta.C[m2] = C[m2];
      d += (long)R[m2] * C[m2];
    }
  }
  transw_kernel<<<9, 256, 0, stream>>>(cvt, tws, ta);
  float* mlp1T = tws + 0,     *mlp2T = tws + 4096,  *wkT = tws + 8192, *wvT = tws + 12288;
  float* wqT   = tws + 16384, *wihT  = tws + 20480, *whhT = tws + 32768;
  float* fc1T  = tws + 45056, *fc2T  = tws + 53248;

  const float* image = ARR(0);
  const float* noise = ARR(1);

  conv5x5<1, float, __hip_bfloat16><<<dim3(64, 4, 16), 256, 0, stream>>>(
      image, ARR(2), ARR(3), act1, 3, 128, 128, 128, 128, 64, 8);
  conv5x5<2, __hip_bfloat16, __hip_bfloat16><<<dim3(16, 4, 16), 256, 0, stream>>>(
      act1, ARR(4), ARR(5), act2, 64, 128, 128, 64, 64, 64, 4);
  conv5x5<2, __hip_bfloat16, float><<<dim3(4, 4, 16), 256, 0, stream>>>(
      act2, ARR(6), ARR(7), act3, 64, 64, 64, 32, 32, 64, 2);
  conv5x5<1, float, float><<<dim3(4, 4, 16), 256, 0, stream>>>(
      act3, ARR(8), ARR(9), act4, 64, 32, 32, 32, 32, 64, 2);

  token_kernel<<<16384, 64, 0, stream>>>(act4, ARR(10), ARR(11),
                                         mlp1T, ARR(13), mlp2T, ARR(15),
                                         ARR(16), ARR(17), wkT, wvT, ARR(21), ARR(22),
                                         knT, vf, lgts);

  sa_kernel<<<16, 1024, 0, stream>>>(knT, vf, lgts, noise, ARR(37), ARR(38),
                                     ARR(25), ARR(26), ARR(23), ARR(24), wqT,
                                     wihT, whhT, ARR(29), ARR(30),
                                     ARR(31), ARR(32), fc1T, ARR(34), fc2T, ARR(36),
                                     (float*)d_out);
#undef ARR
}

// Round 2
// 1483.439 us; speedup vs baseline: 1.0058x; 1.0058x over previous
//
#include <hip/hip_runtime.h>
#include <hip/hip_bf16.h>

// ---------------------------------------------------------------------------
// InvSlotAttentionGuide: CNN encoder -> pos embed -> MLP -> slot attention
// with MESH-Sinkhorn (manual reverse-mode through 5 sinkhorn iters).
// R19: R18 (1024-thr sa_kernel, one token/thread) + amdgpu_waves_per_eu(4,4).
// R18 failed because the backend saw "2 blocks/CU fit by LDS" -> targeted
// 8 waves/EU -> capped VGPR at 64 -> spilled the 14 per-thread Sinkhorn
// floats (WRITE_SIZE 3.7->15.7 MB). Grid is only 16 blocks, so >1 block/CU
// occupancy is worthless: pin waves/EU to 4 -> 128 VGPR cap, no spill.
// ---------------------------------------------------------------------------

#define LN_EPS 1e-5f
#define SEPS 1e-8f
#define LN8 2.0794415416798357f

__device__ inline float ldf(float x) { return x; }
__device__ inline float ldf(__hip_bfloat16 x) { return __bfloat162float(x); }
__device__ inline void stf(float* p, float v) { *p = v; }
__device__ inline void stf(__hip_bfloat16* p, float v) { *p = __float2bfloat16(v); }

__device__ inline float wmaxall(float v) {
#pragma unroll
  for (int o = 32; o; o >>= 1) v = fmaxf(v, __shfl_down(v, o));
  return __shfl(v, 0);
}
__device__ inline float wsumall(float v) {
#pragma unroll
  for (int o = 32; o; o >>= 1) v += __shfl_down(v, o);
  return __shfl(v, 0);
}
__device__ inline int wsumi(int v) {
#pragma unroll
  for (int o = 32; o; o >>= 1) v += __shfl_down(v, o);
  return __shfl(v, 0);
}
__device__ inline float fast_sigmoid(float x) { return 1.f / (1.f + __expf(-x)); }
__device__ inline float fast_tanh(float x) { return 1.f - 2.f / (__expf(2.f * x) + 1.f); }

// ---------------------------------------------------------------------------
__global__ __launch_bounds__(64) void sniff_kernel(const unsigned int* __restrict__ img,
                                                   int* __restrict__ flag) {
  int cnt = 0;
  for (int i = threadIdx.x; i < 512; i += 64) {
    unsigned lo = img[i] & 0xFFFFu;
    int e = (int)((lo >> 7) & 0xFFu);
    cnt += (e >= 96 && e <= 140) ? 1 : 0;
  }
  cnt = wsumi(cnt);
  if (threadIdx.x == 0) *flag = (cnt >= 300) ? 1 : 0;
}

struct CvtArgs {
  const void* src[39];
  long off[40];
};

__global__ __launch_bounds__(256) void convert_kernel(CvtArgs a, const int* __restrict__ flag,
                                                      float* __restrict__ dst, long total) {
  const int isbf = *flag;
  for (long g = (long)blockIdx.x * 256 + threadIdx.x; g < total; g += (long)gridDim.x * 256) {
    int lo = 0, hi = 38;
    while (lo < hi) {
      int mid = (lo + hi + 1) >> 1;
      if (a.off[mid] <= g) lo = mid; else hi = mid - 1;
    }
    long li = g - a.off[lo];
    float v;
    if (isbf) v = __bfloat162float(((const __hip_bfloat16*)a.src[lo])[li]);
    else      v = ((const float*)a.src[lo])[li];
    dst[g] = v;
  }
}

// ---------------------------------------------------------------------------
struct TwArgs {
  long soff[9]; long doff[9]; int R[9]; int C[9];
};

__global__ __launch_bounds__(256) void transw_kernel(const float* __restrict__ cvt,
                                                     float* __restrict__ tws, TwArgs a) {
  int m = blockIdx.x;
  const float* S = cvt + a.soff[m];
  float* D = tws + a.doff[m];
  int R = a.R[m], C = a.C[m];
  for (int idx = threadIdx.x; idx < R * C; idx += 256) {
    int i = idx / C, j = idx - i * C;
    D[j * R + i] = S[idx];
  }
}

// ---------------------------------------------------------------------------
// Direct 5x5 conv + bias + relu (R13-exact): 16x16 tile x 16 oc per block,
// float4 win loads from padded rows, wt[tap][16] broadcast b128.
// ---------------------------------------------------------------------------
template <int S, typename TIN, typename TOUT>
__global__ __launch_bounds__(256) void conv5x5(
    const TIN* __restrict__ in, const float* __restrict__ wgt,
    const float* __restrict__ bias, TOUT* __restrict__ out,
    int Cin, int H, int W, int Ho, int Wo, int Cout, int tilesX) {
  constexpr int P = 15 * S + 5;
  constexpr int PP = (S == 1) ? 20 : 36;
  constexpr int NCH = (S == 1) ? 2 : 3;
  __shared__ __align__(16) float patch[P * PP];
  __shared__ float wt16[25 * 16];
  const int b = blockIdx.z;
  const int ocg = blockIdx.y * 16;
  const int ty0 = (blockIdx.x / tilesX) * 16, tx0 = (blockIdx.x % tilesX) * 16;
  const int og = threadIdx.x >> 6;
  const int r = (threadIdx.x >> 2) & 15;
  const int rx = threadIdx.x & 3;
  const int iy0 = ty0 * S - 2, ix0 = tx0 * S - 2;
  float acc[4][4];
#pragma unroll
  for (int p = 0; p < 4; p++)
#pragma unroll
    for (int j = 0; j < 4; j++) acc[p][j] = 0.f;

  for (int ci = 0; ci < Cin; ++ci) {
    const TIN* inp = in + ((long)b * Cin + ci) * (long)H * W;
    for (int idx = threadIdx.x; idx < P * P; idx += 256) {
      int py = idx / P, px = idx - py * P;
      int iy = iy0 + py, ix = ix0 + px;
      float v = 0.f;
      if (iy >= 0 && iy < H && ix >= 0 && ix < W) v = ldf(inp[(long)iy * W + ix]);
      patch[py * PP + px] = v;
    }
    for (int idx = threadIdx.x; idx < 16 * 25; idx += 256) {
      int tap = idx >> 4, j = idx & 15;
      wt16[idx] = wgt[((long)(ocg + j) * Cin + ci) * 25 + tap];
    }
    __syncthreads();
#pragma unroll
    for (int ky = 0; ky < 5; ky++) {
      float win[4 * NCH];
      const float* bp = &patch[(r * S + ky) * PP + rx * 4 * S];
#pragma unroll
      for (int c = 0; c < NCH; c++) {
        float4 t4 = *(const float4*)(bp + 4 * c);
        win[4 * c + 0] = t4.x;
        win[4 * c + 1] = t4.y;
        win[4 * c + 2] = t4.z;
        win[4 * c + 3] = t4.w;
      }
#pragma unroll
      for (int kx = 0; kx < 5; kx++) {
        const float4 wv = *(const float4*)&wt16[(ky * 5 + kx) * 16 + og * 4];
#pragma unroll
        for (int p = 0; p < 4; p++) {
          float iv = win[p * S + kx];
          acc[p][0] += iv * wv.x;
          acc[p][1] += iv * wv.y;
          acc[p][2] += iv * wv.z;
          acc[p][3] += iv * wv.w;
        }
      }
    }
    __syncthreads();
  }
  const int oy = ty0 + r, ox0 = tx0 + rx * 4;
#pragma unroll
  for (int j = 0; j < 4; j++) {
    int oc = ocg + og * 4 + j;
    float bs = bias[oc];
    TOUT* op = &out[(((long)b * Cout + oc) * Ho + oy) * Wo + ox0];
#pragma unroll
    for (int p = 0; p < 4; p++) stf(&op[p], fmaxf(acc[p][j] + bs, 0.f));
  }
}

// ---------------------------------------------------------------------------
// Per-token (one wave): inline pos-embed from act4 -> MLP -> LN -> k
// (l2norm, stored TRANSPOSED [d][n]), v, mwi logit.  (R13-exact)
// ---------------------------------------------------------------------------
__global__ __launch_bounds__(64) void token_kernel(
    const float* __restrict__ act4, const float* __restrict__ pos_w,
    const float* __restrict__ pos_b,
    const float* __restrict__ mlp1T, const float* __restrict__ mlp1_b,
    const float* __restrict__ mlp2T, const float* __restrict__ mlp2_b,
    const float* __restrict__ lnin_w, const float* __restrict__ lnin_b,
    const float* __restrict__ wkT, const float* __restrict__ wvT,
    const float* __restrict__ mwi_w, const float* __restrict__ mwi_b,
    float* __restrict__ knT_out, float* __restrict__ v_out, float* __restrict__ lg_out) {
  const int t = blockIdx.x, i = threadIdx.x;
  const int b = t >> 10, nn = t & 1023;
  const int h = nn >> 5, w = nn & 31;
  __shared__ float f[64], h1[64], inp[64];
  {
    float gh = h * (1.f / 31.f), gw = w * (1.f / 31.f);
    float e = gh * pos_w[i * 4 + 0] + gw * pos_w[i * 4 + 1] +
              (1.f - gh) * pos_w[i * 4 + 2] + (1.f - gw) * pos_w[i * 4 + 3] + pos_b[i];
    f[i] = act4[(((long)b * 64 + i) * 32 + h) * 32 + w] + e;
  }
  __syncthreads();
  float acc = 0.f;
  for (int j = 0; j < 64; j++) acc += f[j] * mlp1T[j * 64 + i];
  h1[i] = fmaxf(acc + mlp1_b[i], 0.f);
  __syncthreads();
  acc = 0.f;
  for (int j = 0; j < 64; j++) acc += h1[j] * mlp2T[j * 64 + i];
  float x = acc + mlp2_b[i];
  float m = wsumall(x) * (1.f / 64.f);
  float d0 = x - m;
  float var = wsumall(d0 * d0) * (1.f / 64.f);
  float xin = d0 * rsqrtf(var + LN_EPS) * lnin_w[i] + lnin_b[i];
  inp[i] = xin;
  __syncthreads();
  float kv = 0.f, vv = 0.f;
  for (int j = 0; j < 64; j++) {
    float ij = inp[j];
    kv += ij * wkT[j * 64 + i];
    vv += ij * wvT[j * 64 + i];
  }
  float ss = wsumall(kv * kv);
  knT_out[(long)b * 65536 + i * 1024 + nn] = kv / fmaxf(sqrtf(ss), 1e-12f);
  v_out[(long)t * 64 + i] = vv;
  float lg = wsumall(xin * mwi_w[i]);
  if (i == 0) lg_out[t] = lg + mwi_b[0];
}

// ---------------------------------------------------------------------------
// Slot-attention loop (R19): 1024 threads = 16 waves, ONE token per thread.
// amdgpu_waves_per_eu(4,4) pins the occupancy target to our single resident
// block -> 128 VGPR cap -> the 14 per-thread Sinkhorn floats stay in regs.
// Column reductions split 2 waves/slot (8 elems/lane) + LDS combine.
// ---------------------------------------------------------------------------
__global__ __launch_bounds__(1024)
__attribute__((amdgpu_waves_per_eu(4, 4))) void sa_kernel(
    const float* __restrict__ knT_g, const float* __restrict__ v_g,
    const float* __restrict__ la_g, const float* __restrict__ noise,
    const float* __restrict__ mu_w, const float* __restrict__ sg_w,
    const float* __restrict__ lnsl_w, const float* __restrict__ lnsl_b,
    const float* __restrict__ mws_w, const float* __restrict__ mws_b,
    const float* __restrict__ wqT,
    const float* __restrict__ wihT, const float* __restrict__ whhT,
    const float* __restrict__ bih, const float* __restrict__ bhh,
    const float* __restrict__ lnff_w, const float* __restrict__ lnff_b,
    const float* __restrict__ fc1T, const float* __restrict__ fc1_b,
    const float* __restrict__ fc2T, const float* __restrict__ fc2_b,
    float* __restrict__ out) {
  const int b = blockIdx.x, tid = threadIdx.x;
  const int wv = tid >> 6, ln = tid & 63;

  __shared__ float sCt[8192];
  __shared__ float sLa[1024], sU[1024], sGu[1024], sRow[1024], sHid[1024];
  __shared__ float sVh[48], sV[8], sGv[8], sLb[8], sBm[8];
  __shared__ float sWred[32];
  __shared__ float sLaMax;
  __shared__ float sSlots[512], sNorm[512], sQn[512], sUpd[512];

  const float* knt = knT_g + (long)b * 65536;
  const float* vf = v_g + (long)b * 65536;
  float u_hist[5];
  float gPr[8];
  float gInit;

  if (tid < 512) {
    int dd = tid & 63;
    sSlots[tid] = mu_w[dd] + (fabsf(sg_w[dd]) + SEPS) * noise[(long)b * 512 + tid];
  }
  sLa[tid] = la_g[b * 1024 + tid];
  __syncthreads();
  {  // fused la: sLa <- raw - LSE + ln8 ; record laMax  (16-wave version)
    float a0 = sLa[tid];
    float m0 = wmaxall(a0);
    if (ln == 0) sWred[wv] = m0;
    __syncthreads();
    float M = sWred[0];
#pragma unroll
    for (int s = 1; s < 16; s++) M = fmaxf(M, sWred[s]);
    float e0 = wsumall(__expf(a0 - M));
    if (ln == 0) sWred[16 + wv] = e0;
    __syncthreads();
    float SS = 0.f;
#pragma unroll
    for (int s = 0; s < 16; s++) SS += sWred[16 + s];
    float lse = M + __logf(SS);
    sLa[tid] = a0 - lse + LN8;
    if (tid == 0) sLaMax = M - lse + LN8;
  }
  __syncthreads();
  const float laMax = sLaMax;

  for (int it = 0; it < 3; ++it) {
    if (tid < 512) {
      float x = sSlots[tid];
      float m = wsumall(x) * (1.f / 64.f);
      float d0 = x - m;
      float var = wsumall(d0 * d0) * (1.f / 64.f);
      float xn = d0 * rsqrtf(var + LN_EPS) * lnsl_w[ln] + lnsl_b[ln];
      sNorm[tid] = xn;
      float bmv = wsumall(xn * mws_w[ln]);
      if (ln == 0) sBm[wv] = bmv + mws_b[0];
    }
    __syncthreads();
    if (tid == 0) {
      float mx = -1e30f;
      for (int s = 0; s < 8; s++) mx = fmaxf(mx, sBm[s]);
      float ss = 0.f;
      for (int s = 0; s < 8; s++) ss += __expf(sBm[s] - mx);
      float lse = mx + __logf(ss);
      for (int s = 0; s < 8; s++) sLb[s] = sBm[s] - lse + LN8;
    }
    if (tid < 512) {
      float acc = 0.f;
      for (int j = 0; j < 64; j++) acc += sNorm[wv * 64 + j] * wqT[j * 64 + ln];
      sQn[tid] = acc;
    }
    __syncthreads();
    if (tid < 512) {
      float qv = sQn[tid];
      float ss = wsumall(qv * qv);
      sQn[tid] = qv / fmaxf(sqrtf(ss), 1e-12f);
    }
    if (tid < 8) sV[tid] = 0.f;
    __syncthreads();

    {  // C = 1 - kn . qn   (one token per thread)
      const int n = tid;
      float acc[8];
#pragma unroll
      for (int s = 0; s < 8; s++) acc[s] = 0.f;
      for (int j = 0; j < 64; j++) {
        float kvv = knt[j * 1024 + n];
#pragma unroll
        for (int s = 0; s < 8; s++) acc[s] += kvv * sQn[s * 64 + j];
      }
#pragma unroll
      for (int s = 0; s < 8; s++) sCt[s * 1024 + n] = 1.f - acc[s];
    }
    __syncthreads();

    for (int m = 0; m < 4; m++) {
#pragma unroll
      for (int t = 1; t <= 5; t++) {
        if (t == 1 && tid < 8) sVh[tid] = sV[tid];
        {  // row (u) update: one token per thread
          const int n = tid;
          float mx = -1e30f;
#pragma unroll
          for (int s = 0; s < 8; s++) mx = fmaxf(mx, sV[s] - sCt[s * 1024 + n]);
          float ssum = 0.f;
#pragma unroll
          for (int s = 0; s < 8; s++) ssum += __expf(sV[s] - sCt[s * 1024 + n] - mx);
          float un = sLa[n] - (mx + __logf(ssum));
          sU[n] = un;
          u_hist[t - 1] = un;
        }
        __syncthreads();
        {  // column partial: 2 waves/slot, 8 elems/lane
          int s = wv & 7, hf = wv >> 3;
          float ms = laMax - sV[s];
          float ssum = 0.f;
          const int base = hf << 9;
          for (int n = base + ln; n < base + 512; n += 64)
            ssum += __expf(sU[n] - sCt[s * 1024 + n] - ms);
          ssum = wsumall(ssum);
          if (ln == 0) sWred[wv] = ssum;
        }
        __syncthreads();
        if (tid < 8) {
          float ms = laMax - sV[tid];
          float vs = sLb[tid] - (ms + __logf(sWred[tid] + sWred[tid + 8]));
          sV[tid] = vs;
          sVh[t * 8 + tid] = vs;
        }
        __syncthreads();
      }
      {  // entropy gradient seed
        {
          const int n = tid;
          float un = u_hist[4];
          float gul = 0.f;
#pragma unroll
          for (int s = 0; s < 8; s++) {
            float pi = __expf(un + sV[s] - sCt[s * 1024 + n]);
            float gl = -(__logf(pi + SEPS) + pi / (pi + SEPS)) * pi * (1.f / 16.f);
            gPr[s] = gl;
            gul += gl;
          }
          gInit = gul;
        }
        {
          int s = wv & 7, hf = wv >> 3;
          float vs = sV[s];
          float acc = 0.f;
          const int base = hf << 9;
          for (int n = base + ln; n < base + 512; n += 64) {
            float pi = __expf(sU[n] + vs - sCt[s * 1024 + n]);
            acc += -(__logf(pi + SEPS) + pi / (pi + SEPS)) * pi * (1.f / 16.f);
          }
          acc = wsumall(acc);
          if (ln == 0) sWred[wv] = acc;
        }
      }
      __syncthreads();
      if (tid < 8) sGv[tid] = sWred[tid] + sWred[tid + 8];
      __syncthreads();
#pragma unroll
      for (int t = 5; t >= 1; t--) {
        {  // backward row step
          const int n = tid;
          float un = u_hist[t - 1];
          float gul = (t == 5) ? gInit : 0.f;
#pragma unroll
          for (int s = 0; s < 8; s++) {
            float t2 = sGv[s] * __expf(un - sCt[s * 1024 + n] - (sLb[s] - sVh[t * 8 + s]));
            gPr[s] -= t2;
            gul -= t2;
          }
          float rowlse = sLa[n] - un;
#pragma unroll
          for (int s = 0; s < 8; s++)
            gPr[s] -= gul * __expf(sVh[(t - 1) * 8 + s] - sCt[s * 1024 + n] - rowlse);
          sGu[n] = gul;
          sRow[n] = rowlse;
          if (t == 1) {
#pragma unroll
            for (int s = 0; s < 8; s++) sCt[s * 1024 + n] += gPr[s];
          }
        }
        if (t == 1 && tid < 8) sV[tid] = sVh[40 + tid];
        __syncthreads();
        if (t > 1) {
          {  // backward column partial
            int s = wv & 7, hf = wv >> 3;
            float vvh = sVh[(t - 1) * 8 + s];
            float acc = 0.f;
            const int base = hf << 9;
            for (int n = base + ln; n < base + 512; n += 64)
              acc += sGu[n] * __expf(vvh - sCt[s * 1024 + n] - sRow[n]);
            acc = wsumall(acc);
            if (ln == 0) sWred[wv] = acc;
          }
          __syncthreads();
          if (tid < 8) sGv[tid] = -(sWred[tid] + sWred[tid + 8]);
          __syncthreads();
        }
      }
    }

    for (int t = 0; t < 5; t++) {  // final warm-start sinkhorn
      {
        const int n = tid;
        float mx = -1e30f;
#pragma unroll
        for (int s = 0; s < 8; s++) mx = fmaxf(mx, sV[s] - sCt[s * 1024 + n]);
        float ssum = 0.f;
#pragma unroll
        for (int s = 0; s < 8; s++) ssum += __expf(sV[s] - sCt[s * 1024 + n] - mx);
        sU[n] = sLa[n] - (mx + __logf(ssum));
      }
      __syncthreads();
      {
        int s = wv & 7, hf = wv >> 3;
        float ms = laMax - sV[s];
        float ssum = 0.f;
        const int base = hf << 9;
        for (int n = base + ln; n < base + 512; n += 64)
          ssum += __expf(sU[n] - sCt[s * 1024 + n] - ms);
        ssum = wsumall(ssum);
        if (ln == 0) sWred[wv] = ssum;
      }
      __syncthreads();
      if (tid < 8)
        sV[tid] = sLb[tid] - ((laMax - sV[tid]) + __logf(sWred[tid] + sWred[tid + 8]));
      __syncthreads();
    }
    {  // pi
      const int n = tid;
      float un = sU[n];
#pragma unroll
      for (int s = 0; s < 8; s++) sCt[s * 1024 + n] = __expf(un + sV[s] - sCt[s * 1024 + n]);
    }
    __syncthreads();
    if (it == 2) {
      for (int o = tid; o < 8192; o += 1024) out[8192 + (long)b * 8192 + o] = sCt[o];
    }
    {  // updates = attn . v  (split over 2 half-ranges of n, partials in sHid)
      int p = tid >> 9;
      int r = tid & 511;
      int s = r >> 6, dd = r & 63;
      const int base = p << 9;
      float acc = 0.f;
      for (int n = 0; n < 512; n++) acc += sCt[s * 1024 + base + n] * vf[(base + n) * 64 + dd];
      sHid[tid] = acc;
    }
    __syncthreads();
    if (tid < 512) sUpd[tid] = sHid[tid] + sHid[tid + 512];
    __syncthreads();
    float newslot = 0.f;
    if (tid < 512) {  // GRU
      int i = ln;
      const float* x = &sUpd[wv * 64];
      const float* h = &sSlots[wv * 64];
      float gir = 0, giz = 0, gin = 0, ghr = 0, ghz = 0, ghn = 0;
      for (int j = 0; j < 64; j++) {
        float xv = x[j], hv = h[j];
        gir += xv * wihT[j * 192 + i];
        giz += xv * wihT[j * 192 + 64 + i];
        gin += xv * wihT[j * 192 + 128 + i];
        ghr += hv * whhT[j * 192 + i];
        ghz += hv * whhT[j * 192 + 64 + i];
        ghn += hv * whhT[j * 192 + 128 + i];
      }
      gir += bih[i]; giz += bih[64 + i]; gin += bih[128 + i];
      ghr += bhh[i]; ghz += bhh[64 + i]; ghn += bhh[128 + i];
      float rr = fast_sigmoid(gir + ghr);
      float z = fast_sigmoid(giz + ghz);
      float nn = fast_tanh(gin + rr * ghn);
      newslot = (1.f - z) * nn + z * h[i];
    }
    __syncthreads();
    if (tid < 512) sSlots[tid] = newslot;
    __syncthreads();
    if (tid < 512) {
      float x = sSlots[tid];
      float m = wsumall(x) * (1.f / 64.f);
      float d0 = x - m;
      float var = wsumall(d0 * d0) * (1.f / 64.f);
      sNorm[tid] = d0 * rsqrtf(var + LN_EPS) * lnff_w[ln] + lnff_b[ln];
    }
    __syncthreads();
    {  // fc1: one output per thread
      int s = tid >> 7, k2 = tid & 127;
      float acc = 0.f;
      for (int j = 0; j < 64; j++) acc += sNorm[s * 64 + j] * fc1T[j * 128 + k2];
      sHid[tid] = fmaxf(acc + fc1_b[k2], 0.f);
    }
    __syncthreads();
    if (tid < 512) {
      float acc = 0.f;
      for (int j = 0; j < 128; j++) acc += sHid[wv * 128 + j] * fc2T[j * 64 + ln];
      newslot = sSlots[tid] + acc + fc2_b[ln];
    }
    __syncthreads();
    if (tid < 512) sSlots[tid] = newslot;
    __syncthreads();
  }
  if (tid < 512) out[(long)b * 512 + tid] = sSlots[tid];
}

// ---------------------------------------------------------------------------
extern "C" void kernel_launch(void* const* d_in, const int* in_sizes, int n_in,
                              void* d_out, int out_size, void* d_ws, size_t ws_size,
                              hipStream_t stream) {
  (void)n_in; (void)out_size; (void)ws_size;
  char* ws = (char*)d_ws;
  float* cvt  = (float*)ws;                            // f32 inputs (4.7 MB)
  float* lgts = (float*)(ws + 5570560ull);             // RAW logits
  __hip_bfloat16* act1 = (__hip_bfloat16*)(ws + 5636096ull);   // bf16 33.55MB
  __hip_bfloat16* act2 = (__hip_bfloat16*)(ws + 39190528ull);  // bf16  8.39MB
  float* act3 = (float*)(ws + 5636096ull);             // over dead act1
  float* act4 = (float*)(ws + 9830400ull);             // live through token
  float* knT  = (float*)(ws + 14024704ull);            // 4 MB
  float* vf   = (float*)(ws + 18219008ull);            // 4 MB
  int*   flag = (int*)(ws + 47579136ull);
  float* tws  = (float*)(ws + 47583232ull);            // transposed weights

  CvtArgs ca;
  long total = 0;
  for (int i = 0; i < 39; i++) { ca.src[i] = d_in[i]; ca.off[i] = total; total += in_sizes[i]; }
  ca.off[39] = total;

  sniff_kernel<<<1, 64, 0, stream>>>((const unsigned int*)d_in[0], flag);
  convert_kernel<<<1024, 256, 0, stream>>>(ca, flag, cvt, total);

#define ARR(i) (cvt + ca.off[i])
  TwArgs ta;
  {
    const int src[9] = {12, 14, 18, 19, 20, 27, 28, 33, 35};
    const int R[9] = {64, 64, 64, 64, 64, 192, 192, 128, 64};
    const int C[9] = {64, 64, 64, 64, 64, 64, 64, 64, 128};
    long d = 0;
    for (int m2 = 0; m2 < 9; m2++) {
      ta.soff[m2] = ca.off[src[m2]];
      ta.doff[m2] = d;
      ta.R[m2] = R[m2];
      ta.C[m2] = C[m2];
      d += (long)R[m2] * C[m2];
    }
  }
  transw_kernel<<<9, 256, 0, stream>>>(cvt, tws, ta);
  float* mlp1T = tws + 0,     *mlp2T = tws + 4096,  *wkT = tws + 8192, *wvT = tws + 12288;
  float* wqT   = tws + 16384, *wihT  = tws + 20480, *whhT = tws + 32768;
  float* fc1T  = tws + 45056, *fc2T  = tws + 53248;

  const float* image = ARR(0);
  const float* noise = ARR(1);

  conv5x5<1, float, __hip_bfloat16><<<dim3(64, 4, 16), 256, 0, stream>>>(
      image, ARR(2), ARR(3), act1, 3, 128, 128, 128, 128, 64, 8);
  conv5x5<2, __hip_bfloat16, __hip_bfloat16><<<dim3(16, 4, 16), 256, 0, stream>>>(
      act1, ARR(4), ARR(5), act2, 64, 128, 128, 64, 64, 64, 4);
  conv5x5<2, __hip_bfloat16, float><<<dim3(4, 4, 16), 256, 0, stream>>>(
      act2, ARR(6), ARR(7), act3, 64, 64, 64, 32, 32, 64, 2);
  conv5x5<1, float, float><<<dim3(4, 4, 16), 256, 0, stream>>>(
      act3, ARR(8), ARR(9), act4, 64, 32, 32, 32, 32, 64, 2);

  token_kernel<<<16384, 64, 0, stream>>>(act4, ARR(10), ARR(11),
                                         mlp1T, ARR(13), mlp2T, ARR(15),
                                         ARR(16), ARR(17), wkT, wvT, ARR(21), ARR(22),
                                         knT, vf, lgts);

  sa_kernel<<<16, 1024, 0, stream>>>(knT, vf, lgts, noise, ARR(37), ARR(38),
                                     ARR(25), ARR(26), ARR(23), ARR(24), wqT,
                                     wihT, whhT, ARR(29), ARR(30),
                                     ARR(31), ARR(32), fc1T, ARR(34), fc2T, ARR(36),
                                     (float*)d_out);
#undef ARR
}